// Round 10
// baseline (9785.822 us; speedup 1.0000x reference)
//
#include <hip/hip_runtime.h>
#include <math.h>

// ---------------- problem constants ----------------
#define TN   256
#define TWM  64
#define TR   4
#define TH   512
#define TD   512
#define TT   128
#define TB   32
#define IFACE 471
#define EPSI 1e-6f

// ---------------- workspace layout (floats) ----------------
#define OFF_H      0          // 2 x 32*512 ping-pong
#define OFF_C      32768
#define OFF_M      49152      // 32*256*64
#define OFF_USAGE  573440
#define OFF_RW     581632     // 32*4*256
#define OFF_WW     614400
#define OFF_PRECA  622592     // prec ping/pong (2 x 8192)
#define OFF_LINK   638976     // 32*256*256
#define OFF_RVEC   2736128
#define OFF_MNORM  2744320    // 32*256
#define OFF_ZP     2752512    // (unused now)
#define OFF_PARSE  2998272    // 32 x 448 parsed interface
#define OFF_CRS    3012608    // 32 x 4 x 256 cr logits
#define OFF_FW     3045376    // 32 x 4 x 256
#define OFF_BWP    3078144    // 256 x 4 x 256 bw chunk partials
#define OFF_CNT    3340288    // counters x 16 floats
#define TOTAL_STATE 3341696

// counters (each on its own 64B line), all monotonic across t
#define CNT_GALL   (OFF_CNT + 0*16)            // aggregate gates-done counter
#define CNT_SB(b)  (OFF_CNT + (8+(b))*16)      // 32 stepB tail counters
#define CNT_FA(b)  (OFF_CNT + (40+(b))*16)     // 32 stepA done flags

__device__ __forceinline__ float sigm(float x)  { return 1.0f / (1.0f + expf(-x)); }
__device__ __forceinline__ float softpl(float x){ return x > 20.0f ? x : log1pf(expf(x)); }

// ---- device-coherent (MALL) access, used ONLY for same-dispatch handoffs ----
__device__ __forceinline__ float ldc(const float* p) {
    return __hip_atomic_load(p, __ATOMIC_RELAXED, __HIP_MEMORY_SCOPE_AGENT);
}
__device__ __forceinline__ void stc(float* p, float v) {
    __hip_atomic_store(p, v, __ATOMIC_RELAXED, __HIP_MEMORY_SCOPE_AGENT);
}
__device__ __forceinline__ float4 ldcv4(const float* p) {
    float4 v;
    v.x = ldc(p); v.y = ldc(p + 1); v.z = ldc(p + 2); v.w = ldc(p + 3);
    return v;
}
__device__ __forceinline__ void stcv4(float* p, float4 v) {
    stc(p, v.x); stc(p + 1, v.y); stc(p + 2, v.z); stc(p + 3, v.w);
}
__device__ __forceinline__ unsigned ldcu(const unsigned* p) {
    return __hip_atomic_load(p, __ATOMIC_RELAXED, __HIP_MEMORY_SCOPE_AGENT);
}

__device__ __forceinline__ int outswz(int raw) {
    return (((raw >> 2) & 3) << 5) | ((raw & 3) << 3) | (raw >> 4);
}

// ---------------- init ----------------
__global__ void k_init(float* ws) {
    int idx = blockIdx.x * 256 + threadIdx.x;
    if (idx >= TOTAL_STATE) return;
    float v = 0.0f;
    if (idx >= OFF_M && idx < OFF_M + TB*TN*TWM) v = EPSI;
    if (idx >= OFF_MNORM && idx < OFF_MNORM + TB*TN) v = 8e-6f;
    ws[idx] = v;
}

// ---------------- out(t-1) GEMM device fn (prev-dispatch inputs: plain) ----------------
__device__ __forceinline__ void out_phase(
    const float* __restrict__ W_pre, const float* __restrict__ b_pre,
    const float* __restrict__ W_rout, const float* __restrict__ ws,
    float* __restrict__ out, float* sm, const int tid, const int B2, const int t)
{
    float* act_s = sm;          // 4 batches x 768
    float* red_s = sm + 3072;   // 16 ksub x 4 b x 32 col
    const int q = B2 >> 5, s = (B2 >> 3) & 3, bg = B2 & 7, b0 = bg * 4;
    for (int i = tid; i < 768; i += 512) {
        const int bb = i / 192;
        const int k0 = (i - bb*192) * 4;
        const float* src = (k0 < 512) ? &ws[OFF_H + (t&1)*(TB*TH) + (b0+bb)*TH + k0]
                                      : &ws[OFF_RVEC + (b0+bb)*256 + (k0 - 512)];
        *(float4*)&act_s[bb*768 + k0] = *(const float4*)src;
    }
    __syncthreads();
    const int c0 = q*128 + s*32;
    const int col = tid & 31;
    const int ksb = tid >> 5;
    float a0=0, a1=0, a2=0, a3=0;
    for (int kk = ksb*48; kk < ksb*48 + 48; ++kk) {
        const float w = (kk < 512) ? W_pre[(size_t)kk * 512 + c0 + col]
                                   : W_rout[(size_t)(kk - 512) * 512 + c0 + col];
        a0 += act_s[kk]        * w;
        a1 += act_s[768 + kk]  * w;
        a2 += act_s[1536 + kk] * w;
        a3 += act_s[2304 + kk] * w;
    }
    red_s[(ksb*4 + 0)*32 + col] = a0;
    red_s[(ksb*4 + 1)*32 + col] = a1;
    red_s[(ksb*4 + 2)*32 + col] = a2;
    red_s[(ksb*4 + 3)*32 + col] = a3;
    __syncthreads();
    if (tid < 128) {
        const int cc = tid & 31, bb = tid >> 5;
        float ssum = 0.0f;
        #pragma unroll
        for (int ks2 = 0; ks2 < 16; ++ks2) ssum += red_s[(ks2*4 + bb)*32 + cc];
        ssum += b_pre[c0 + cc];
        out[(size_t)(t - 1) * (TB * TD) + (b0+bb) * TD + c0 + cc] = ssum;
    }
    __syncthreads();
}

// ---------------- stepA device fn (h via ldc; inline z GEMV; WW/PARSE via stc) ----------------
__device__ void stepA_fn(const float* __restrict__ W_if, const float* __restrict__ b_if,
                         float* __restrict__ ws,
                         const int t, const int b, const int tid, float* sm)
{
    float* z_s      = sm + 0;
    float* rwf_s    = sm + 480;
    float* ww_old_s = sm + 1504;
    float* ww_s     = sm + 1760;
    float* u_s      = sm + 2016;
    float* prec_s   = sm + 2272;
    float* mnorm_s  = sm + 2528;
    float* alloc_s  = sm + 2784;
    float* cw_s     = sm + 3040;
    float* keysp    = sm + 3296;
    float* wkey_s   = sm + 3552;
    float* erase_s  = sm + 3616;
    float* wvec_s   = sm + 3680;
    float* rstr_s   = sm + 3744;
    float* free_s   = sm + 3748;
    float* modesp   = sm + 3752;
    float* knorm_s  = sm + 3764;
    float* sredA_s  = sm + 3772;
    float* sc_s     = sm + 3780;
    float* Pt_s     = sm + 3788;   // 512 -> ends 4300
    float* h_s      = sm + 4304;   // 512 -> ends 4816

    const float* wsM = ws + OFF_M + b * (TN * TWM);
    const float* precOld = ws + OFF_PRECA + (t & 1) * (TB * TN) + b * 256;
    float* precNew = ws + OFF_PRECA + ((t + 1) & 1) * (TB * TN) + b * 256;

    // ---- stage: prev-dispatch data plain; h(t+1) via ldc (same-dispatch gates) ----
    if (tid < 256)       { *(float4*)&rwf_s[tid*4] = *(const float4*)&ws[OFF_RW + b*1024 + tid*4]; }
    else if (tid < 320)  { const int i = tid-256; *(float4*)&ww_old_s[i*4] = *(const float4*)&ws[OFF_WW + b*256 + i*4]; }
    else if (tid < 384)  { const int i = tid-320; *(float4*)&u_s[i*4]      = *(const float4*)&ws[OFF_USAGE + b*256 + i*4]; }
    else if (tid < 448)  { const int i = tid-384; *(float4*)&prec_s[i*4]   = *(const float4*)&precOld[i*4]; }
    else                 { const int i = tid-448; *(float4*)&mnorm_s[i*4]  = *(const float4*)&ws[OFF_MNORM + b*256 + i*4]; }
    h_s[tid] = ldc(&ws[OFF_H + ((t+1)&1)*(TB*TH) + b*TH + tid]);
    __syncthreads();

    // ---- z = h @ W_if + b_if (inline GEMV; W_if plain, L2-resident) ----
    if (tid < IFACE) {
        float zv = b_if[tid];
        const float* wb = W_if + tid;
        #pragma unroll 8
        for (int k = 0; k < TH; ++k)
            zv += h_s[k] * wb[(size_t)k * IFACE];
        z_s[tid] = zv;
    }
    __syncthreads();

    // ---- parse ----
    if (tid < IFACE) {
        const float v = z_s[tid];
        if (tid < 256)       keysp[(tid >> 6)*64 + (tid & 63)] = v;
        else if (tid < 260)  rstr_s[tid - 256] = 1.0f + softpl(v);
        else if (tid < 324)  wkey_s[tid - 260] = v;
        else if (tid == 324) sc_s[0] = 1.0f + softpl(v);
        else if (tid < 389)  erase_s[tid - 325] = sigm(v);
        else if (tid < 453)  wvec_s[tid - 389] = v;
        else if (tid < 457)  free_s[tid - 453] = sigm(v);
        else if (tid == 457) sc_s[1] = sigm(v);
        else if (tid == 458) sc_s[2] = sigm(v);
    }
    __syncthreads();
    if (tid < 320) {
        const int w5 = tid >> 6, lane = tid & 63;
        const float v = (w5 == 0) ? wkey_s[lane] : keysp[(w5 - 1)*64 + lane];
        float s = v * v;
        #pragma unroll
        for (int m = 1; m <= 32; m <<= 1) s += __shfl_xor(s, m);
        if (lane == 0) knorm_s[w5] = fmaxf(sqrtf(s), EPSI);
    } else if (tid >= 508) {
        const int r = tid - 508;
        const float m0 = z_s[459 + r*3], m1 = z_s[460 + r*3], m2 = z_s[461 + r*3];
        const float mx = fmaxf(m0, fmaxf(m1, m2));
        const float e0 = expf(m0 - mx), e1 = expf(m1 - mx), e2 = expf(m2 - mx);
        const float s = e0 + e1 + e2;
        modesp[r*3+0] = e0 / s; modesp[r*3+1] = e1 / s; modesp[r*3+2] = e2 / s;
    }
    __syncthreads();

    if (tid < 404) {
        float v;
        if (tid < 256)       v = keysp[tid];
        else if (tid < 320)  v = erase_s[tid - 256];
        else if (tid < 384)  v = wvec_s[tid - 320];
        else if (tid < 388)  v = rstr_s[tid - 384];
        else if (tid < 392)  v = knorm_s[tid - 388 + 1];
        else                 v = modesp[tid - 392];
        stc(&ws[OFF_PARSE + b * 448 + tid], v);
    }
    if (tid < 256) {
        float ret = 1.0f;
        #pragma unroll
        for (int r = 0; r < 4; ++r) ret *= 1.0f - free_s[r] * rwf_s[r*256 + tid];
        const float un = (u_s[tid] + ww_old_s[tid] - u_s[tid] * ww_old_s[tid]) * ret;
        u_s[tid] = un;
        ws[OFF_USAGE + b * 256 + tid] = un;   // next dispatch: plain
    }
    __syncthreads();

    {
        const int q = tid >> 8, n = tid & 255;
        const float un = u_s[n];
        float p = 1.0f;
        #pragma unroll 8
        for (int m = q * 128; m < q * 128 + 128; ++m) {
            const float um = u_s[m];
            const bool lt = (um < un) || (um == un && m < n);
            p *= lt ? um : 1.0f;
        }
        Pt_s[q * 256 + n] = p;
    }
    __syncthreads();
    if (tid < 256)
        alloc_s[tid] = (1.0f - u_s[tid]) * Pt_s[tid] * Pt_s[256 + tid];
    __syncthreads();

    {
        const int n = tid >> 1, q2 = tid & 1;
        const float* mp = wsM + n * 64 + q2 * 32;
        float s = 0.0f;
        #pragma unroll
        for (int it = 0; it < 8; ++it) {
            float4 mv = *(const float4*)(mp + it * 4);
            float4 kv = *(const float4*)&wkey_s[q2 * 32 + it * 4];
            s += mv.x*kv.x + mv.y*kv.y + mv.z*kv.z + mv.w*kv.w;
        }
        s += __shfl_xor(s, 1);
        if (q2 == 0) cw_s[n] = sc_s[0] * s / (knorm_s[0] * mnorm_s[n]);
    }
    __syncthreads();
    {
        float v = 0.0f, e = 0.0f;
        if (tid < 256) {
            v = cw_s[tid];
            float m = v;
            #pragma unroll
            for (int mm = 1; mm <= 32; mm <<= 1) m = fmaxf(m, __shfl_xor(m, mm));
            if ((tid & 63) == 0) sredA_s[tid >> 6] = m;
        }
        __syncthreads();
        if (tid == 0) sc_s[4] = fmaxf(fmaxf(sredA_s[0], sredA_s[1]), fmaxf(sredA_s[2], sredA_s[3]));
        __syncthreads();
        if (tid < 256) {
            e = expf(v - sc_s[4]);
            float s2 = e;
            #pragma unroll
            for (int mm = 1; mm <= 32; mm <<= 1) s2 += __shfl_xor(s2, mm);
            if ((tid & 63) == 0) sredA_s[tid >> 6] = s2;
        }
        __syncthreads();
        if (tid == 0) sc_s[5] = sredA_s[0] + sredA_s[1] + sredA_s[2] + sredA_s[3];
        __syncthreads();
        if (tid < 256) cw_s[tid] = e / sc_s[5];
    }
    __syncthreads();

    if (tid < 256) {
        const float wwn = sc_s[2] * (sc_s[1] * alloc_s[tid] + (1.0f - sc_s[1]) * cw_s[tid]);
        ww_s[tid] = wwn;
        stc(&ws[OFF_WW + b * 256 + tid], wwn);
    }
    __syncthreads();
    if (tid < 256) {
        float s = ww_s[tid];
        #pragma unroll
        for (int mm = 1; mm <= 32; mm <<= 1) s += __shfl_xor(s, mm);
        if ((tid & 63) == 0) sredA_s[tid >> 6] = s;
    }
    __syncthreads();
    if (tid == 0) sc_s[3] = sredA_s[0] + sredA_s[1] + sredA_s[2] + sredA_s[3];
    __syncthreads();
    if (tid < 256)
        precNew[tid] = (1.0f - sc_s[3]) * prec_s[tid] + ww_s[tid];  // next dispatch: plain
}

// ---------------- stepB device fn (same-dispatch data via ldc) ----------------
__device__ void stepB_fn(float* __restrict__ ws, const int t, const int b,
                         const int tid, float* sm)
{
    float* crp     = sm;          // 4 x 256
    float* rw2_s   = sm + 1024;   // 1024
    float* Lt2     = sm + 2048;   // 2048
    float* md      = sm + 4096;   // 12
    float* sredA_s = sm + 4112;   // 8
    float* sredB_s = sm + 4120;   // 8
    float* gmax_s  = sm + 4128;   // 4
    float* gsum_s  = sm + 4132;   // 4
    const float* wsM = ws + OFF_M + b * (TN * TWM);

    crp[tid]       = ldc(&ws[OFF_CRS + b*1024 + tid]);
    crp[tid + 512] = ldc(&ws[OFF_CRS + b*1024 + tid + 512]);
    if (tid < 12) md[tid] = ldc(&ws[OFF_PARSE + b*448 + 392 + tid]);
    __syncthreads();

    {
        const int rr = tid >> 8, n = tid & 255, wv = tid >> 6, lane = tid & 63;
        float v0 = crp[rr*256 + n], v1 = crp[(rr + 2)*256 + n];
        float m0 = v0, m1 = v1;
        #pragma unroll
        for (int mm = 1; mm <= 32; mm <<= 1) {
            m0 = fmaxf(m0, __shfl_xor(m0, mm));
            m1 = fmaxf(m1, __shfl_xor(m1, mm));
        }
        if (lane == 0) { sredA_s[wv] = m0; sredB_s[wv] = m1; }
        __syncthreads();
        if (tid < 4) {
            const float* base = (tid & 2) ? sredB_s : sredA_s;
            const int off = (tid & 1) * 4;
            gmax_s[tid] = fmaxf(fmaxf(base[off], base[off+1]), fmaxf(base[off+2], base[off+3]));
        }
        __syncthreads();
        const float e0 = expf(v0 - gmax_s[rr]);
        const float e1 = expf(v1 - gmax_s[rr + 2]);
        float s0 = e0, s1 = e1;
        #pragma unroll
        for (int mm = 1; mm <= 32; mm <<= 1) {
            s0 += __shfl_xor(s0, mm); s1 += __shfl_xor(s1, mm);
        }
        if (lane == 0) { sredA_s[wv] = s0; sredB_s[wv] = s1; }
        __syncthreads();
        if (tid < 4) {
            const float* base = (tid & 2) ? sredB_s : sredA_s;
            const int off = (tid & 1) * 4;
            gsum_s[tid] = base[off] + base[off+1] + base[off+2] + base[off+3];
        }
        __syncthreads();
        crp[rr*256 + n]       = e0 / gsum_s[rr];
        crp[(rr + 2)*256 + n] = e1 / gsum_s[rr + 2];
    }
    __syncthreads();

    {
        const int rr = tid >> 8, n = tid & 255;
        #pragma unroll
        for (int p = 0; p < 2; ++p) {
            const int r = rr + 2 * p;
            float part[8];
            #pragma unroll
            for (int c = 0; c < 8; ++c)
                part[c] = ldc(&ws[OFF_BWP + (size_t)(b*8 + c)*1024 + r*256 + n]);
            const float fwv = ldc(&ws[OFF_FW + b*1024 + r*256 + n]);
            float bw = 0.0f;
            #pragma unroll
            for (int c = 0; c < 8; ++c) bw += part[c];
            const float v = md[r*3] * bw + md[r*3+1] * crp[r*256 + n] + md[r*3+2] * fwv;
            rw2_s[r*256 + n] = v;
            ws[OFF_RW + b*1024 + r*256 + n] = v;   // next dispatch: plain
        }
    }
    __syncthreads();

    {
        const int g8 = tid >> 6, w = tid & 63;
        float p0=0, p1=0, p2=0, p3=0;
        const float* mb = wsM + (size_t)(g8 * 32) * 64 + w;
        for (int gg = 0; gg < 4; ++gg) {
            float mv[8];
            #pragma unroll
            for (int j = 0; j < 8; ++j) mv[j] = ldc(mb + (gg*8 + j) * 64);
            #pragma unroll
            for (int j = 0; j < 8; ++j) {
                const int n = g8*32 + gg*8 + j;
                p0 += rw2_s[n]       * mv[j];
                p1 += rw2_s[256 + n] * mv[j];
                p2 += rw2_s[512 + n] * mv[j];
                p3 += rw2_s[768 + n] * mv[j];
            }
        }
        Lt2[(g8*4 + 0)*64 + w] = p0;
        Lt2[(g8*4 + 1)*64 + w] = p1;
        Lt2[(g8*4 + 2)*64 + w] = p2;
        Lt2[(g8*4 + 3)*64 + w] = p3;
    }
    __syncthreads();
    if (tid < 256) {
        const int r = tid >> 6, w = tid & 63;
        float s = 0.0f;
        #pragma unroll
        for (int g = 0; g < 8; ++g) s += Lt2[(g*4 + r)*64 + w];
        ws[OFF_RVEC + b * 256 + tid] = s;          // next dispatch: plain
    }
}

// ---------------- THE step kernel: gates || stepA(dedicated) || out -> link -> stepB ----------------
__global__ __launch_bounds__(512) void k_all(
    const float* __restrict__ emb, const float* __restrict__ Wx,
    const float* __restrict__ Wh,  const float* __restrict__ b_lstm,
    const float* __restrict__ W_pre, const float* __restrict__ b_pre,
    const float* __restrict__ W_rout,
    const float* __restrict__ W_if, const float* __restrict__ b_if,
    float* __restrict__ ws, float* __restrict__ out, int t)
{
    __shared__ __align__(16) float sm[16384];   // 64 KB, reused per phase
    __shared__ int isTail;
    const int tid = threadIdx.x;
    const int blk = blockIdx.x;

    if (t >= TT) {
        // final dispatch: only out(TT-1)
        if (blk >= 160) {
            const int j0 = blk - 160;
            out_phase(W_pre, b_pre, W_rout, ws, out, sm, tid, outswz(j0), t);
            if (j0 < 32)
                out_phase(W_pre, b_pre, W_rout, ws, out, sm, tid, outswz(96 + j0), t);
        }
        return;
    }

    if (blk < 128) {
        // ===== gates (4 u-cols per block) =====
        const int ublk = ((blk & 7) << 4) | (blk >> 3);
        const int u0  = ublk * 4;
        {
            const int cg  = tid & 3;
            const int bg  = (tid >> 2) & 7;
            const int ks  = tid >> 5;
            const int col0 = cg * 512 + u0;
            const float* hbuf = ws + OFF_H + (t & 1) * (TB * TH);

            float acc[4][4] = {};

            for (int tile = 0; tile < 5; ++tile) {
                const int T0 = tile * 256;
                {
                    const int b = tid & 31, kf4 = tid >> 5;
                    #pragma unroll
                    for (int i = 0; i < 4; ++i) {
                        const int kf = kf4 * 4 + i;
                        const int kl = kf * 4;
                        const int k  = T0 + kl;
                        const float* src;
                        if (k < 512)      src = emb + (size_t)t * (TB*TD) + b * TD + k;
                        else if (k < 768) src = ws + OFF_RVEC + b * 256 + (k - 512);
                        else              src = hbuf + b * TH + (k - 768);
                        float4 v = *(const float4*)src;
                        sm[(kl+0)*32 + b] = v.x;
                        sm[(kl+1)*32 + b] = v.y;
                        sm[(kl+2)*32 + b] = v.z;
                        sm[(kl+3)*32 + b] = v.w;
                    }
                }
                __syncthreads();
                {
                    const int k0 = T0 + ks * 16;
                    const float* wp = (k0 < 768 ? Wx + (size_t)k0 * 2048
                                                : Wh + (size_t)(k0 - 768) * 2048) + col0;
                    const float* ap = &sm[(ks * 16) * 32 + bg * 4];
                    #pragma unroll 8
                    for (int kk = 0; kk < 16; ++kk) {
                        float4 wv = *(const float4*)wp; wp += 2048;
                        float4 av = *(const float4*)ap; ap += 32;
                        acc[0][0] += wv.x*av.x; acc[0][1] += wv.x*av.y; acc[0][2] += wv.x*av.z; acc[0][3] += wv.x*av.w;
                        acc[1][0] += wv.y*av.x; acc[1][1] += wv.y*av.y; acc[1][2] += wv.y*av.z; acc[1][3] += wv.y*av.w;
                        acc[2][0] += wv.z*av.x; acc[2][1] += wv.z*av.y; acc[2][2] += wv.z*av.z; acc[2][3] += wv.z*av.w;
                        acc[3][0] += wv.w*av.x; acc[3][1] += wv.w*av.y; acc[3][2] += wv.w*av.z; acc[3][3] += wv.w*av.w;
                    }
                }
                __syncthreads();
            }

            {
                const int rbase = 8192 + ks * 512 + (cg * 8 + bg) * 16;
                *(float4*)&sm[rbase + 0]  = make_float4(acc[0][0], acc[0][1], acc[0][2], acc[0][3]);
                *(float4*)&sm[rbase + 4]  = make_float4(acc[1][0], acc[1][1], acc[1][2], acc[1][3]);
                *(float4*)&sm[rbase + 8]  = make_float4(acc[2][0], acc[2][1], acc[2][2], acc[2][3]);
                *(float4*)&sm[rbase + 12] = make_float4(acc[3][0], acc[3][1], acc[3][2], acc[3][3]);
            }
            __syncthreads();
            {
                const int o = tid;
                float s = 0.0f;
                #pragma unroll
                for (int kq = 0; kq < 16; ++kq) s += sm[8192 + kq * 512 + o];
                const int ocg = o >> 7, obg = (o >> 4) & 7, odu = (o >> 2) & 3, obb = o & 3;
                s += b_lstm[ocg * 512 + u0 + odu];
                sm[(ocg * 4 + odu) * 32 + (obg * 4 + obb)] = s;
            }
            __syncthreads();
            if (tid < 128) {
                const int du = tid >> 5, b = tid & 31;
                const float ig = sm[(0  + du) * 32 + b];
                const float fg = sm[(4  + du) * 32 + b];
                const float gg = sm[(8  + du) * 32 + b];
                const float og = sm[(12 + du) * 32 + b];
                const int ci = b * TH + u0 + du;
                const float cold = ws[OFF_C + ci];        // block-local
                const float cn = sigm(fg) * cold + sigm(ig) * tanhf(gg);
                const float hn = sigm(og) * tanhf(cn);
                ws[OFF_C + ci] = cn;                      // block-local
                stc(&ws[OFF_H + ((t + 1) & 1) * (TB * TH) + ci], hn);  // same-dispatch stepA reads
            }
        }
        asm volatile("s_waitcnt vmcnt(0)" ::: "memory");
        __syncthreads();
        if (tid == 0)
            __hip_atomic_fetch_add((unsigned*)(ws + CNT_GALL), 1u,
                                   __ATOMIC_RELAXED, __HIP_MEMORY_SCOPE_AGENT);
    } else if (blk < 160) {
        // ===== dedicated stepA (one batch per block) =====
        const int ab = blk - 128;
        if (tid == 0) {
            const unsigned* p = (const unsigned*)(ws + CNT_GALL);
            while (ldcu(p) < 128u * (unsigned)(t + 1)) __builtin_amdgcn_s_sleep(1);
        }
        __syncthreads();
        stepA_fn(W_if, b_if, ws, t, ab, tid, sm);
        asm volatile("s_waitcnt vmcnt(0)" ::: "memory");
        __syncthreads();
        if (tid == 0)
            __hip_atomic_store((unsigned*)(ws + CNT_FA(ab)), (unsigned)(t + 1),
                               __ATOMIC_RELAXED, __HIP_MEMORY_SCOPE_AGENT);
        __syncthreads();
    } else {
        // ===== out(t-1): 96 blocks cover 128 jobs =====
        if (t > 0) {
            const int j0 = blk - 160;
            out_phase(W_pre, b_pre, W_rout, ws, out, sm, tid, outswz(j0), t);
            if (j0 < 32)
                out_phase(W_pre, b_pre, W_rout, ws, out, sm, tid, outswz(96 + j0), t);
        }
    }

    // ===== link for (b, c): PRELOAD self-owned/prev-dispatch data, THEN wait =====
    const int b = blk >> 3;
    const int c = blk & 7;
    {
        float* ww_s   = sm;          // 256
        float* prec_s = sm + 256;    // 256
        float* rw_s   = sm + 512;    // 1024
        float* pk_s   = sm + 1536;   // 448
        float* Lt     = sm + 2048;   // 32*257 = 8224
        const float* precOld = ws + OFF_PRECA + (t & 1) * (TB * TN) + b * 256;

        // ---- preload during the stepA-wait shadow ----
        float4 m_pre;
        {
            const int ric = tid >> 4, c4 = (tid & 15) * 4;
            const int gi  = c * 32 + ric;
            m_pre = *(const float4*)(ws + OFF_M + b * (TN*TWM) + gi * 64 + c4);
        }
        float lpre[16];
        {
            const int j = tid & 255, p = tid >> 8;
            #pragma unroll
            for (int it = 0; it < 16; ++it) {
                const int ric = it * 2 + p;
                lpre[it] = ws[OFF_LINK + (size_t)b * (TN*TN) + (size_t)(c*32 + ric) * 256 + j];
            }
        }
        if (tid < 256)      { *(float4*)&rw_s[tid*4] = *(const float4*)&ws[OFF_RW + b*1024 + tid*4]; }
        else if (tid < 320) { const int i = tid-256; *(float4*)&prec_s[i*4] = *(const float4*)&precOld[i*4]; }

        // ---- wait for stepA[b] ----
        if (tid == 0) {
            const unsigned* fa = (const unsigned*)(ws + CNT_FA(b));
            while (ldcu(fa) < (unsigned)(t + 1)) __builtin_amdgcn_s_sleep(1);
        }
        __syncthreads();

        // ---- post-wait coherent loads (same-dispatch stepA outputs only) ----
        if (tid < 64)                      { *(float4*)&ww_s[tid*4] = ldcv4(&ws[OFF_WW + b*256 + tid*4]); }
        else if (tid >= 384 && tid < 496)  { const int i = tid-384; *(float4*)&pk_s[i*4] = ldcv4(&ws[OFF_PARSE + b*448 + i*4]); }
        __syncthreads();

        // ---- M update + norms + cr logits ----
        {
            const int ric = tid >> 4, c4 = (tid & 15) * 4;
            const int gi  = c * 32 + ric;
            float* mp = ws + OFF_M + b * (TN*TWM) + gi * 64 + c4;
            float4 m = m_pre;
            const float wwi = ww_s[gi];
            float4 er = *(const float4*)&pk_s[256 + c4];
            float4 wv = *(const float4*)&pk_s[320 + c4];
            m.x = m.x * (1.0f - wwi * er.x) + wwi * wv.x;
            m.y = m.y * (1.0f - wwi * er.y) + wwi * wv.y;
            m.z = m.z * (1.0f - wwi * er.z) + wwi * wv.z;
            m.w = m.w * (1.0f - wwi * er.w) + wwi * wv.w;
            stcv4(mp, m);
            float sn = m.x*m.x + m.y*m.y + m.z*m.z + m.w*m.w;
            float d0 = m.x*pk_s[c4]     + m.y*pk_s[c4+1]     + m.z*pk_s[c4+2]     + m.w*pk_s[c4+3];
            float d1 = m.x*pk_s[64+c4]  + m.y*pk_s[64+c4+1]  + m.z*pk_s[64+c4+2]  + m.w*pk_s[64+c4+3];
            float d2 = m.x*pk_s[128+c4] + m.y*pk_s[128+c4+1] + m.z*pk_s[128+c4+2] + m.w*pk_s[128+c4+3];
            float d3 = m.x*pk_s[192+c4] + m.y*pk_s[192+c4+1] + m.z*pk_s[192+c4+2] + m.w*pk_s[192+c4+3];
            #pragma unroll
            for (int mm = 1; mm <= 8; mm <<= 1) {
                sn += __shfl_xor(sn, mm);
                d0 += __shfl_xor(d0, mm); d1 += __shfl_xor(d1, mm);
                d2 += __shfl_xor(d2, mm); d3 += __shfl_xor(d3, mm);
            }
            if ((tid & 15) == 0) {
                const float mn = fmaxf(sqrtf(sn), EPSI);
                ws[OFF_MNORM + b*256 + gi] = mn;   // next dispatch: plain
                const float inv = 1.0f / mn;
                stc(&ws[OFF_CRS + b*1024 + 0*256 + gi], pk_s[384+0] * d0 * inv / pk_s[388+0]);
                stc(&ws[OFF_CRS + b*1024 + 1*256 + gi], pk_s[384+1] * d1 * inv / pk_s[388+1]);
                stc(&ws[OFF_CRS + b*1024 + 2*256 + gi], pk_s[384+2] * d2 * inv / pk_s[388+2]);
                stc(&ws[OFF_CRS + b*1024 + 3*256 + gi], pk_s[384+3] * d3 * inv / pk_s[388+3]);
            }
        }

        // ---- link rows update (preloaded lpre; plain write, block-local) ----
        {
            const int j = tid & 255, p = tid >> 8;
            const float wwj = ww_s[j], pj = prec_s[j];
            #pragma unroll 4
            for (int it = 0; it < 16; ++it) {
                const int ric = it * 2 + p;
                const int gi  = c * 32 + ric;
                float* lp = ws + OFF_LINK + (size_t)b * (TN*TN) + (size_t)gi * 256 + j;
                const float wwi = ww_s[gi];
                float v = (1.0f - wwi - wwj) * lpre[it] + wwi * pj;
                if (j == gi) v = 0.0f;
                *lp = v;
                Lt[ric * 257 + j] = v;
            }
        }
        __syncthreads();

        // ---- fw ----
        {
            const int ric = tid >> 4, g = tid & 15;
            const int gi = c * 32 + ric;
            float f0=0, f1=0, f2=0, f3=0;
            #pragma unroll 4
            for (int jj = 0; jj < 16; ++jj) {
                const int j = g * 16 + jj;
                const float v = Lt[ric * 257 + j];
                f0 += v * rw_s[j]; f1 += v * rw_s[256+j];
                f2 += v * rw_s[512+j]; f3 += v * rw_s[768+j];
            }
            #pragma unroll
            for (int mm = 1; mm <= 8; mm <<= 1) {
                f0 += __shfl_xor(f0, mm); f1 += __shfl_xor(f1, mm);
                f2 += __shfl_xor(f2, mm); f3 += __shfl_xor(f3, mm);
            }
            if (g == 0) {
                stc(&ws[OFF_FW + b*1024 + gi],       f0);
                stc(&ws[OFF_FW + b*1024 + 256 + gi], f1);
                stc(&ws[OFF_FW + b*1024 + 512 + gi], f2);
                stc(&ws[OFF_FW + b*1024 + 768 + gi], f3);
            }
        }

        // ---- bw partials ----
        {
            const int j = tid & 255, p = tid >> 8;
            float b0=0, b1=0, b2=0, b3=0;
            #pragma unroll 4
            for (int it = 0; it < 16; ++it) {
                const int ric = p * 16 + it;
                const int gi  = c * 32 + ric;
                const float v = Lt[ric * 257 + j];
                b0 += v * rw_s[gi]; b1 += v * rw_s[256+gi];
                b2 += v * rw_s[512+gi]; b3 += v * rw_s[768+gi];
            }
            __syncthreads();
            if (p == 1) { Lt[j] = b0; Lt[256+j] = b1; Lt[512+j] = b2; Lt[768+j] = b3; }
            __syncthreads();
            if (p == 0) {
                stc(&ws[OFF_BWP + (size_t)blk*1024 + j],       b0 + Lt[j]);
                stc(&ws[OFF_BWP + (size_t)blk*1024 + 256 + j], b1 + Lt[256+j]);
                stc(&ws[OFF_BWP + (size_t)blk*1024 + 512 + j], b2 + Lt[512+j]);
                stc(&ws[OFF_BWP + (size_t)blk*1024 + 768 + j], b3 + Lt[768+j]);
            }
        }
    }

    // ===== stepB tail (last of the 8 chunk blocks per batch) =====
    asm volatile("s_waitcnt vmcnt(0)" ::: "memory");
    __syncthreads();
    if (tid == 0) {
        unsigned* cnt = (unsigned*)(ws + CNT_SB(b));
        const unsigned old = __hip_atomic_fetch_add(cnt, 1u, __ATOMIC_RELAXED, __HIP_MEMORY_SCOPE_AGENT);
        isTail = (old == 8u * (unsigned)t + 7u) ? 1 : 0;
    }
    __syncthreads();
    if (!isTail) return;
    stepB_fn(ws, t, b, tid, sm);
}

extern "C" void kernel_launch(void* const* d_in, const int* in_sizes, int n_in,
                              void* d_out, int out_size, void* d_ws, size_t ws_size,
                              hipStream_t stream) {
    const float* emb    = (const float*)d_in[0];
    const float* Wx     = (const float*)d_in[1];
    const float* Wh     = (const float*)d_in[2];
    const float* b_lstm = (const float*)d_in[3];
    const float* W_pre  = (const float*)d_in[4];
    const float* b_pre  = (const float*)d_in[5];
    const float* W_if   = (const float*)d_in[6];
    const float* b_if   = (const float*)d_in[7];
    const float* W_rout = (const float*)d_in[8];
    float* out = (float*)d_out;
    float* ws  = (float*)d_ws;

    k_init<<<(TOTAL_STATE + 255) / 256, 256, 0, stream>>>(ws);
    for (int t = 0; t < TT; ++t) {
        k_all<<<256, 512, 0, stream>>>(emb, Wx, Wh, b_lstm, W_pre, b_pre, W_rout,
                                       W_if, b_if, ws, out, t);
    }
    // final out(127)
    k_all<<<256, 512, 0, stream>>>(emb, Wx, Wh, b_lstm, W_pre, b_pre, W_rout,
                                   W_if, b_if, ws, out, TT);
}

// Round 11
// 7054.533 us; speedup vs baseline: 1.3872x; 1.3872x over previous
//
#include <hip/hip_runtime.h>
#include <math.h>

// ---------------- problem constants ----------------
#define TN   256
#define TWM  64
#define TR   4
#define TH   512
#define TD   512
#define TT   128
#define TB   32
#define IFACE 471
#define EPSI 1e-6f

// ---------------- workspace layout (floats) ----------------
#define OFF_H      0          // 2 x 32*512 ping-pong
#define OFF_C      32768
#define OFF_M      49152      // 32*256*64
#define OFF_USAGE  573440
#define OFF_RW     581632     // 32*4*256
#define OFF_WW     614400
#define OFF_PRECA  622592     // prec ping/pong (2 x 8192)
#define OFF_LINK   638976     // 32*256*256
#define OFF_RVEC   2736128
#define OFF_MNORM  2744320    // 32*256
#define OFF_ZP     2752512    // 16 x 32 x 480 z partials
#define OFF_PARSE  2998272    // 32 x 448 parsed interface
#define OFF_CRS    3012608    // 32 x 4 x 256 cr logits
#define OFF_FW     3045376    // 32 x 4 x 256
#define OFF_BWP    3078144    // 256 x 4 x 256 bw chunk partials
#define OFF_CNT    3340288    // 88 counters x 16 floats
#define TOTAL_STATE 3341696

// counters (each on its own 64B line), all monotonic across t
#define CNT_ZPG(g) (OFF_CNT + (g)*16)          // 8 zp group counters
#define CNT_SB(b)  (OFF_CNT + (8+(b))*16)      // 32 stepB tail counters
#define CNT_FA(b)  (OFF_CNT + (40+(b))*16)     // 32 stepA done flags
#define CNT_GG(g)  (OFF_CNT + (72+(g))*16)     // 16 gates col-group counters

__device__ __forceinline__ float sigm(float x)  { return 1.0f / (1.0f + expf(-x)); }
__device__ __forceinline__ float softpl(float x){ return x > 20.0f ? x : log1pf(expf(x)); }

// ---- device-coherent (MALL) access, used ONLY for same-dispatch handoffs ----
__device__ __forceinline__ float ldc(const float* p) {
    return __hip_atomic_load(p, __ATOMIC_RELAXED, __HIP_MEMORY_SCOPE_AGENT);
}
__device__ __forceinline__ void stc(float* p, float v) {
    __hip_atomic_store(p, v, __ATOMIC_RELAXED, __HIP_MEMORY_SCOPE_AGENT);
}
__device__ __forceinline__ float4 ldcv4(const float* p) {
    float4 v;
    v.x = ldc(p); v.y = ldc(p + 1); v.z = ldc(p + 2); v.w = ldc(p + 3);
    return v;
}
__device__ __forceinline__ void stcv4(float* p, float4 v) {
    stc(p, v.x); stc(p + 1, v.y); stc(p + 2, v.z); stc(p + 3, v.w);
}
__device__ __forceinline__ unsigned ldcu(const unsigned* p) {
    return __hip_atomic_load(p, __ATOMIC_RELAXED, __HIP_MEMORY_SCOPE_AGENT);
}

// ---------------- init ----------------
__global__ void k_init(float* ws) {
    int idx = blockIdx.x * 256 + threadIdx.x;
    if (idx >= TOTAL_STATE) return;
    float v = 0.0f;
    if (idx >= OFF_M && idx < OFF_M + TB*TN*TWM) v = EPSI;
    if (idx >= OFF_MNORM && idx < OFF_MNORM + TB*TN) v = 8e-6f;
    ws[idx] = v;
}

// ---------------- out(t-1) GEMM device fn (prev-dispatch inputs: plain) ----------------
__device__ __forceinline__ void out_phase(
    const float* __restrict__ W_pre, const float* __restrict__ b_pre,
    const float* __restrict__ W_rout, const float* __restrict__ ws,
    float* __restrict__ out, float* sm, const int tid, const int B2, const int t)
{
    float* act_s = sm;          // 4 batches x 768
    float* red_s = sm + 3072;   // 16 ksub x 4 b x 32 col
    const int q = B2 >> 5, s = (B2 >> 3) & 3, bg = B2 & 7, b0 = bg * 4;
    for (int i = tid; i < 768; i += 512) {
        const int bb = i / 192;
        const int k0 = (i - bb*192) * 4;
        const float* src = (k0 < 512) ? &ws[OFF_H + (t&1)*(TB*TH) + (b0+bb)*TH + k0]
                                      : &ws[OFF_RVEC + (b0+bb)*256 + (k0 - 512)];
        *(float4*)&act_s[bb*768 + k0] = *(const float4*)src;
    }
    __syncthreads();
    const int c0 = q*128 + s*32;
    const int col = tid & 31;
    const int ksb = tid >> 5;
    float a0=0, a1=0, a2=0, a3=0;
    for (int kk = ksb*48; kk < ksb*48 + 48; ++kk) {
        const float w = (kk < 512) ? W_pre[(size_t)kk * 512 + c0 + col]
                                   : W_rout[(size_t)(kk - 512) * 512 + c0 + col];
        a0 += act_s[kk]        * w;
        a1 += act_s[768 + kk]  * w;
        a2 += act_s[1536 + kk] * w;
        a3 += act_s[2304 + kk] * w;
    }
    red_s[(ksb*4 + 0)*32 + col] = a0;
    red_s[(ksb*4 + 1)*32 + col] = a1;
    red_s[(ksb*4 + 2)*32 + col] = a2;
    red_s[(ksb*4 + 3)*32 + col] = a3;
    __syncthreads();
    if (tid < 128) {
        const int cc = tid & 31, bb = tid >> 5;
        float ssum = 0.0f;
        #pragma unroll
        for (int ks2 = 0; ks2 < 16; ++ks2) ssum += red_s[(ks2*4 + bb)*32 + cc];
        ssum += b_pre[c0 + cc];
        out[(size_t)(t - 1) * (TB * TD) + (b0+bb) * TD + c0 + cc] = ssum;
    }
    __syncthreads();
}

// ---------------- stepA device fn (ZP via ldc; WW/PARSE via stc) ----------------
__device__ void stepA_fn(const float* __restrict__ b_if, float* __restrict__ ws,
                         const int t, const int b, const int tid, float* sm)
{
    float* z_s      = sm + 0;
    float* rwf_s    = sm + 480;
    float* ww_old_s = sm + 1504;
    float* ww_s     = sm + 1760;
    float* u_s      = sm + 2016;
    float* prec_s   = sm + 2272;
    float* mnorm_s  = sm + 2528;
    float* alloc_s  = sm + 2784;
    float* cw_s     = sm + 3040;
    float* keysp    = sm + 3296;
    float* wkey_s   = sm + 3552;
    float* erase_s  = sm + 3616;
    float* wvec_s   = sm + 3680;
    float* rstr_s   = sm + 3744;
    float* free_s   = sm + 3748;
    float* modesp   = sm + 3752;
    float* knorm_s  = sm + 3764;
    float* sredA_s  = sm + 3772;
    float* sc_s     = sm + 3780;
    float* Pt_s     = sm + 3788;   // 512 -> ends 4300

    const float* wsM = ws + OFF_M + b * (TN * TWM);
    const float* precOld = ws + OFF_PRECA + (t & 1) * (TB * TN) + b * 256;
    float* precNew = ws + OFF_PRECA + ((t + 1) & 1) * (TB * TN) + b * 256;

    if (tid < 256)       { *(float4*)&rwf_s[tid*4] = *(const float4*)&ws[OFF_RW + b*1024 + tid*4]; }
    else if (tid < 320)  { const int i = tid-256; *(float4*)&ww_old_s[i*4] = *(const float4*)&ws[OFF_WW + b*256 + i*4]; }
    else if (tid < 384)  { const int i = tid-320; *(float4*)&u_s[i*4]      = *(const float4*)&ws[OFF_USAGE + b*256 + i*4]; }
    else if (tid < 448)  { const int i = tid-384; *(float4*)&prec_s[i*4]   = *(const float4*)&precOld[i*4]; }
    else                 { const int i = tid-448; *(float4*)&mnorm_s[i*4]  = *(const float4*)&ws[OFF_MNORM + b*256 + i*4]; }
    if (tid < IFACE) {
        float part[16];
        #pragma unroll
        for (int p = 0; p < 16; ++p)
            part[p] = ldc(&ws[OFF_ZP + ((size_t)p*32 + b) * 480 + tid]);
        float zv = b_if[tid];
        #pragma unroll
        for (int p = 0; p < 16; ++p) zv += part[p];
        z_s[tid] = zv;
    }
    __syncthreads();

    if (tid < IFACE) {
        const float v = z_s[tid];
        if (tid < 256)       keysp[(tid >> 6)*64 + (tid & 63)] = v;
        else if (tid < 260)  rstr_s[tid - 256] = 1.0f + softpl(v);
        else if (tid < 324)  wkey_s[tid - 260] = v;
        else if (tid == 324) sc_s[0] = 1.0f + softpl(v);
        else if (tid < 389)  erase_s[tid - 325] = sigm(v);
        else if (tid < 453)  wvec_s[tid - 389] = v;
        else if (tid < 457)  free_s[tid - 453] = sigm(v);
        else if (tid == 457) sc_s[1] = sigm(v);
        else if (tid == 458) sc_s[2] = sigm(v);
    }
    __syncthreads();
    if (tid < 320) {
        const int w5 = tid >> 6, lane = tid & 63;
        const float v = (w5 == 0) ? wkey_s[lane] : keysp[(w5 - 1)*64 + lane];
        float s = v * v;
        #pragma unroll
        for (int m = 1; m <= 32; m <<= 1) s += __shfl_xor(s, m);
        if (lane == 0) knorm_s[w5] = fmaxf(sqrtf(s), EPSI);
    } else if (tid >= 508) {
        const int r = tid - 508;
        const float m0 = z_s[459 + r*3], m1 = z_s[460 + r*3], m2 = z_s[461 + r*3];
        const float mx = fmaxf(m0, fmaxf(m1, m2));
        const float e0 = expf(m0 - mx), e1 = expf(m1 - mx), e2 = expf(m2 - mx);
        const float s = e0 + e1 + e2;
        modesp[r*3+0] = e0 / s; modesp[r*3+1] = e1 / s; modesp[r*3+2] = e2 / s;
    }
    __syncthreads();

    if (tid < 404) {
        float v;
        if (tid < 256)       v = keysp[tid];
        else if (tid < 320)  v = erase_s[tid - 256];
        else if (tid < 384)  v = wvec_s[tid - 320];
        else if (tid < 388)  v = rstr_s[tid - 384];
        else if (tid < 392)  v = knorm_s[tid - 388 + 1];
        else                 v = modesp[tid - 392];
        stc(&ws[OFF_PARSE + b * 448 + tid], v);
    }
    if (tid < 256) {
        float ret = 1.0f;
        #pragma unroll
        for (int r = 0; r < 4; ++r) ret *= 1.0f - free_s[r] * rwf_s[r*256 + tid];
        const float un = (u_s[tid] + ww_old_s[tid] - u_s[tid] * ww_old_s[tid]) * ret;
        u_s[tid] = un;
        ws[OFF_USAGE + b * 256 + tid] = un;   // next dispatch: plain
    }
    __syncthreads();

    {
        const int q = tid >> 8, n = tid & 255;
        const float un = u_s[n];
        float p = 1.0f;
        #pragma unroll 8
        for (int m = q * 128; m < q * 128 + 128; ++m) {
            const float um = u_s[m];
            const bool lt = (um < un) || (um == un && m < n);
            p *= lt ? um : 1.0f;
        }
        Pt_s[q * 256 + n] = p;
    }
    __syncthreads();
    if (tid < 256)
        alloc_s[tid] = (1.0f - u_s[tid]) * Pt_s[tid] * Pt_s[256 + tid];
    __syncthreads();

    {
        const int n = tid >> 1, q2 = tid & 1;
        const float* mp = wsM + n * 64 + q2 * 32;
        float s = 0.0f;
        #pragma unroll
        for (int it = 0; it < 8; ++it) {
            float4 mv = *(const float4*)(mp + it * 4);
            float4 kv = *(const float4*)&wkey_s[q2 * 32 + it * 4];
            s += mv.x*kv.x + mv.y*kv.y + mv.z*kv.z + mv.w*kv.w;
        }
        s += __shfl_xor(s, 1);
        if (q2 == 0) cw_s[n] = sc_s[0] * s / (knorm_s[0] * mnorm_s[n]);
    }
    __syncthreads();
    {
        float v = 0.0f, e = 0.0f;
        if (tid < 256) {
            v = cw_s[tid];
            float m = v;
            #pragma unroll
            for (int mm = 1; mm <= 32; mm <<= 1) m = fmaxf(m, __shfl_xor(m, mm));
            if ((tid & 63) == 0) sredA_s[tid >> 6] = m;
        }
        __syncthreads();
        if (tid == 0) sc_s[4] = fmaxf(fmaxf(sredA_s[0], sredA_s[1]), fmaxf(sredA_s[2], sredA_s[3]));
        __syncthreads();
        if (tid < 256) {
            e = expf(v - sc_s[4]);
            float s2 = e;
            #pragma unroll
            for (int mm = 1; mm <= 32; mm <<= 1) s2 += __shfl_xor(s2, mm);
            if ((tid & 63) == 0) sredA_s[tid >> 6] = s2;
        }
        __syncthreads();
        if (tid == 0) sc_s[5] = sredA_s[0] + sredA_s[1] + sredA_s[2] + sredA_s[3];
        __syncthreads();
        if (tid < 256) cw_s[tid] = e / sc_s[5];
    }
    __syncthreads();

    if (tid < 256) {
        const float wwn = sc_s[2] * (sc_s[1] * alloc_s[tid] + (1.0f - sc_s[1]) * cw_s[tid]);
        ww_s[tid] = wwn;
        stc(&ws[OFF_WW + b * 256 + tid], wwn);
    }
    __syncthreads();
    if (tid < 256) {
        float s = ww_s[tid];
        #pragma unroll
        for (int mm = 1; mm <= 32; mm <<= 1) s += __shfl_xor(s, mm);
        if ((tid & 63) == 0) sredA_s[tid >> 6] = s;
    }
    __syncthreads();
    if (tid == 0) sc_s[3] = sredA_s[0] + sredA_s[1] + sredA_s[2] + sredA_s[3];
    __syncthreads();
    if (tid < 256)
        precNew[tid] = (1.0f - sc_s[3]) * prec_s[tid] + ww_s[tid];  // next dispatch: plain
}

// ---------------- stepB device fn (same-dispatch data via ldc) ----------------
__device__ void stepB_fn(float* __restrict__ ws, const int t, const int b,
                         const int tid, float* sm)
{
    float* crp     = sm;          // 4 x 256
    float* rw2_s   = sm + 1024;   // 1024
    float* Lt2     = sm + 2048;   // 2048
    float* md      = sm + 4096;   // 12
    float* sredA_s = sm + 4112;   // 8
    float* sredB_s = sm + 4120;   // 8
    float* gmax_s  = sm + 4128;   // 4
    float* gsum_s  = sm + 4132;   // 4
    const float* wsM = ws + OFF_M + b * (TN * TWM);

    crp[tid]       = ldc(&ws[OFF_CRS + b*1024 + tid]);
    crp[tid + 512] = ldc(&ws[OFF_CRS + b*1024 + tid + 512]);
    if (tid < 12) md[tid] = ldc(&ws[OFF_PARSE + b*448 + 392 + tid]);
    __syncthreads();

    {
        const int rr = tid >> 8, n = tid & 255, wv = tid >> 6, lane = tid & 63;
        float v0 = crp[rr*256 + n], v1 = crp[(rr + 2)*256 + n];
        float m0 = v0, m1 = v1;
        #pragma unroll
        for (int mm = 1; mm <= 32; mm <<= 1) {
            m0 = fmaxf(m0, __shfl_xor(m0, mm));
            m1 = fmaxf(m1, __shfl_xor(m1, mm));
        }
        if (lane == 0) { sredA_s[wv] = m0; sredB_s[wv] = m1; }
        __syncthreads();
        if (tid < 4) {
            const float* base = (tid & 2) ? sredB_s : sredA_s;
            const int off = (tid & 1) * 4;
            gmax_s[tid] = fmaxf(fmaxf(base[off], base[off+1]), fmaxf(base[off+2], base[off+3]));
        }
        __syncthreads();
        const float e0 = expf(v0 - gmax_s[rr]);
        const float e1 = expf(v1 - gmax_s[rr + 2]);
        float s0 = e0, s1 = e1;
        #pragma unroll
        for (int mm = 1; mm <= 32; mm <<= 1) {
            s0 += __shfl_xor(s0, mm); s1 += __shfl_xor(s1, mm);
        }
        if (lane == 0) { sredA_s[wv] = s0; sredB_s[wv] = s1; }
        __syncthreads();
        if (tid < 4) {
            const float* base = (tid & 2) ? sredB_s : sredA_s;
            const int off = (tid & 1) * 4;
            gsum_s[tid] = base[off] + base[off+1] + base[off+2] + base[off+3];
        }
        __syncthreads();
        crp[rr*256 + n]       = e0 / gsum_s[rr];
        crp[(rr + 2)*256 + n] = e1 / gsum_s[rr + 2];
    }
    __syncthreads();

    {
        const int rr = tid >> 8, n = tid & 255;
        #pragma unroll
        for (int p = 0; p < 2; ++p) {
            const int r = rr + 2 * p;
            float part[8];
            #pragma unroll
            for (int c = 0; c < 8; ++c)
                part[c] = ldc(&ws[OFF_BWP + (size_t)(b*8 + c)*1024 + r*256 + n]);
            const float fwv = ldc(&ws[OFF_FW + b*1024 + r*256 + n]);
            float bw = 0.0f;
            #pragma unroll
            for (int c = 0; c < 8; ++c) bw += part[c];
            const float v = md[r*3] * bw + md[r*3+1] * crp[r*256 + n] + md[r*3+2] * fwv;
            rw2_s[r*256 + n] = v;
            ws[OFF_RW + b*1024 + r*256 + n] = v;   // next dispatch: plain
        }
    }
    __syncthreads();

    {
        const int g8 = tid >> 6, w = tid & 63;
        float p0=0, p1=0, p2=0, p3=0;
        const float* mb = wsM + (size_t)(g8 * 32) * 64 + w;
        for (int gg = 0; gg < 4; ++gg) {
            float mv[8];
            #pragma unroll
            for (int j = 0; j < 8; ++j) mv[j] = ldc(mb + (gg*8 + j) * 64);
            #pragma unroll
            for (int j = 0; j < 8; ++j) {
                const int n = g8*32 + gg*8 + j;
                p0 += rw2_s[n]       * mv[j];
                p1 += rw2_s[256 + n] * mv[j];
                p2 += rw2_s[512 + n] * mv[j];
                p3 += rw2_s[768 + n] * mv[j];
            }
        }
        Lt2[(g8*4 + 0)*64 + w] = p0;
        Lt2[(g8*4 + 1)*64 + w] = p1;
        Lt2[(g8*4 + 2)*64 + w] = p2;
        Lt2[(g8*4 + 3)*64 + w] = p3;
    }
    __syncthreads();
    if (tid < 256) {
        const int r = tid >> 6, w = tid & 63;
        float s = 0.0f;
        #pragma unroll
        for (int g = 0; g < 8; ++g) s += Lt2[(g*4 + r)*64 + w];
        ws[OFF_RVEC + b * 256 + tid] = s;          // next dispatch: plain
    }
}

// ---------------- THE step kernel: gates||out -> zp -> stepA -> link -> stepB ----------------
__global__ __launch_bounds__(512) void k_all(
    const float* __restrict__ emb, const float* __restrict__ Wx,
    const float* __restrict__ Wh,  const float* __restrict__ b_lstm,
    const float* __restrict__ W_pre, const float* __restrict__ b_pre,
    const float* __restrict__ W_rout,
    const float* __restrict__ W_if, const float* __restrict__ b_if,
    float* __restrict__ ws, float* __restrict__ out, int t)
{
    __shared__ __align__(16) float sm[16384];   // 64 KB, reused per phase
    __shared__ int myBatch;
    __shared__ int isTail;
    const int tid = threadIdx.x;
    const int blk = blockIdx.x;

    if (blk >= 128) {
        // ===== out(t-1) =====
        if (t > 0) {
            const int raw2 = blk - 128;
            const int B2 = (((raw2 >> 2) & 3) << 5) | ((raw2 & 3) << 3) | (raw2 >> 4);
            out_phase(W_pre, b_pre, W_rout, ws, out, sm, tid, B2, t);
        }
    } else if (t < TT) {
        // ===== gates (4 u-cols per block) =====
        const int ublk = ((blk & 7) << 4) | (blk >> 3);
        const int u0  = ublk * 4;
        {
            const int cg  = tid & 3;
            const int bg  = (tid >> 2) & 7;
            const int ks  = tid >> 5;
            const int col0 = cg * 512 + u0;
            const float* hbuf = ws + OFF_H + (t & 1) * (TB * TH);

            float acc[4][4] = {};

            for (int tile = 0; tile < 5; ++tile) {
                const int T0 = tile * 256;
                {
                    const int b = tid & 31, kf4 = tid >> 5;
                    #pragma unroll
                    for (int i = 0; i < 4; ++i) {
                        const int kf = kf4 * 4 + i;
                        const int kl = kf * 4;
                        const int k  = T0 + kl;
                        const float* src;
                        if (k < 512)      src = emb + (size_t)t * (TB*TD) + b * TD + k;
                        else if (k < 768) src = ws + OFF_RVEC + b * 256 + (k - 512);
                        else              src = hbuf + b * TH + (k - 768);
                        float4 v = *(const float4*)src;
                        sm[(kl+0)*32 + b] = v.x;
                        sm[(kl+1)*32 + b] = v.y;
                        sm[(kl+2)*32 + b] = v.z;
                        sm[(kl+3)*32 + b] = v.w;
                    }
                }
                __syncthreads();
                {
                    const int k0 = T0 + ks * 16;
                    const float* wp = (k0 < 768 ? Wx + (size_t)k0 * 2048
                                                : Wh + (size_t)(k0 - 768) * 2048) + col0;
                    const float* ap = &sm[(ks * 16) * 32 + bg * 4];
                    #pragma unroll 8
                    for (int kk = 0; kk < 16; ++kk) {
                        float4 wv = *(const float4*)wp; wp += 2048;
                        float4 av = *(const float4*)ap; ap += 32;
                        acc[0][0] += wv.x*av.x; acc[0][1] += wv.x*av.y; acc[0][2] += wv.x*av.z; acc[0][3] += wv.x*av.w;
                        acc[1][0] += wv.y*av.x; acc[1][1] += wv.y*av.y; acc[1][2] += wv.y*av.z; acc[1][3] += wv.y*av.w;
                        acc[2][0] += wv.z*av.x; acc[2][1] += wv.z*av.y; acc[2][2] += wv.z*av.z; acc[2][3] += wv.z*av.w;
                        acc[3][0] += wv.w*av.x; acc[3][1] += wv.w*av.y; acc[3][2] += wv.w*av.z; acc[3][3] += wv.w*av.w;
                    }
                }
                __syncthreads();
            }

            {
                const int rbase = 8192 + ks * 512 + (cg * 8 + bg) * 16;
                *(float4*)&sm[rbase + 0]  = make_float4(acc[0][0], acc[0][1], acc[0][2], acc[0][3]);
                *(float4*)&sm[rbase + 4]  = make_float4(acc[1][0], acc[1][1], acc[1][2], acc[1][3]);
                *(float4*)&sm[rbase + 8]  = make_float4(acc[2][0], acc[2][1], acc[2][2], acc[2][3]);
                *(float4*)&sm[rbase + 12] = make_float4(acc[3][0], acc[3][1], acc[3][2], acc[3][3]);
            }
            __syncthreads();
            {
                const int o = tid;
                float s = 0.0f;
                #pragma unroll
                for (int kq = 0; kq < 16; ++kq) s += sm[8192 + kq * 512 + o];
                const int ocg = o >> 7, obg = (o >> 4) & 7, odu = (o >> 2) & 3, obb = o & 3;
                s += b_lstm[ocg * 512 + u0 + odu];
                sm[(ocg * 4 + odu) * 32 + (obg * 4 + obb)] = s;
            }
            __syncthreads();
            if (tid < 128) {
                const int du = tid >> 5, b = tid & 31;
                const float ig = sm[(0  + du) * 32 + b];
                const float fg = sm[(4  + du) * 32 + b];
                const float gg = sm[(8  + du) * 32 + b];
                const float og = sm[(12 + du) * 32 + b];
                const int ci = b * TH + u0 + du;
                const float cold = ws[OFF_C + ci];        // block-local
                const float cn = sigm(fg) * cold + sigm(ig) * tanhf(gg);
                const float hn = sigm(og) * tanhf(cn);
                ws[OFF_C + ci] = cn;                      // block-local
                stc(&ws[OFF_H + ((t + 1) & 1) * (TB * TH) + ci], hn);  // same-dispatch zp reads
            }
        }
        asm volatile("s_waitcnt vmcnt(0)" ::: "memory");
        __syncthreads();
        if (tid == 0)
            __hip_atomic_fetch_add((unsigned*)(ws + CNT_GG(ublk >> 3)), 1u,
                                   __ATOMIC_RELAXED, __HIP_MEMORY_SCOPE_AGENT);

        // ===== zp (wait only for own col-group: 8 gates blocks) =====
        const int bgz = blk >> 4;
        const int q = (blk >> 2) & 3, s = blk & 3;
        const int b0 = bgz * 4;
        if (tid == 0) {
            const unsigned* gg = (const unsigned*)(ws + CNT_GG(q*4 + s));
            while (ldcu(gg) < 8u * (unsigned)(t + 1)) __builtin_amdgcn_s_sleep(1);
        }
        __syncthreads();
        {
            float* h1_s = sm;
            if (tid < 128) {
                const int bb = tid >> 5, kk = tid & 31;
                h1_s[bb*32 + kk] = ldc(&ws[OFF_H + ((t+1)&1)*(TB*TH) + (b0+bb)*TH + q*128 + s*32 + kk]);
            }
            __syncthreads();
            if (tid < IFACE) {
                const int col = tid;
                float a0=0, a1=0, a2=0, a3=0;
                const float* wb = W_if + (size_t)(q*128 + s*32) * IFACE + col;
                #pragma unroll 8
                for (int kk = 0; kk < 32; ++kk) {
                    const float w = *wb; wb += IFACE;
                    a0 += h1_s[kk]      * w;
                    a1 += h1_s[32+kk]   * w;
                    a2 += h1_s[64+kk]   * w;
                    a3 += h1_s[96+kk]   * w;
                }
                const size_t base = OFF_ZP + ((size_t)(q*4+s)*32 + b0) * 480 + col;
                stc(&ws[base],        a0);
                stc(&ws[base + 480],  a1);
                stc(&ws[base + 960],  a2);
                stc(&ws[base + 1440], a3);
            }
        }
        asm volatile("s_waitcnt vmcnt(0)" ::: "memory");
        __syncthreads();
        if (tid == 0) {
            unsigned* cnt = (unsigned*)(ws + CNT_ZPG(bgz));
            const unsigned old = __hip_atomic_fetch_add(cnt, 1u, __ATOMIC_RELAXED, __HIP_MEMORY_SCOPE_AGENT);
            const unsigned base = 16u * (unsigned)t;
            int mb = -1;
            if (old >= base + 12u) {   // last 4 arrivers: stepA for one batch each
                mb = b0 + (int)(old - (base + 12u));
                while (ldcu(cnt) < base + 16u) __builtin_amdgcn_s_sleep(1);
            }
            myBatch = mb;
        }
        __syncthreads();
        if (myBatch >= 0) {
            stepA_fn(b_if, ws, t, myBatch, tid, sm);
            asm volatile("s_waitcnt vmcnt(0)" ::: "memory");
            __syncthreads();
            if (tid == 0)
                __hip_atomic_store((unsigned*)(ws + CNT_FA(myBatch)), (unsigned)(t + 1),
                                   __ATOMIC_RELAXED, __HIP_MEMORY_SCOPE_AGENT);
        }
        __syncthreads();
    }

    if (t >= TT) return;

    // ===== link for (b, c): PRELOAD self-owned/prev-dispatch data, THEN wait =====
    const int b = blk >> 3;
    const int c = blk & 7;
    {
        float* ww_s   = sm;          // 256
        float* prec_s = sm + 256;    // 256
        float* rw_s   = sm + 512;    // 1024
        float* pk_s   = sm + 1536;   // 448
        float* Lt     = sm + 2048;   // 32*257 = 8224
        const float* precOld = ws + OFF_PRECA + (t & 1) * (TB * TN) + b * 256;

        // ---- preload into registers/LDS during the stepA-wait shadow ----
        float4 m_pre;
        {
            const int ric = tid >> 4, c4 = (tid & 15) * 4;
            const int gi  = c * 32 + ric;
            m_pre = *(const float4*)(ws + OFF_M + b * (TN*TWM) + gi * 64 + c4);
        }
        float lpre[16];
        {
            const int j = tid & 255, p = tid >> 8;
            #pragma unroll
            for (int it = 0; it < 16; ++it) {
                const int ric = it * 2 + p;
                lpre[it] = ws[OFF_LINK + (size_t)b * (TN*TN) + (size_t)(c*32 + ric) * 256 + j];
            }
        }
        if (tid < 256)      { *(float4*)&rw_s[tid*4] = *(const float4*)&ws[OFF_RW + b*1024 + tid*4]; }
        else if (tid < 320) { const int i = tid-256; *(float4*)&prec_s[i*4] = *(const float4*)&precOld[i*4]; }

        // ---- wait for stepA[b] ----
        if (tid == 0) {
            const unsigned* fa = (const unsigned*)(ws + CNT_FA(b));
            while (ldcu(fa) < (unsigned)(t + 1)) __builtin_amdgcn_s_sleep(1);
        }
        __syncthreads();

        // ---- post-wait coherent loads (same-dispatch stepA outputs only) ----
        if (tid < 64)                      { *(float4*)&ww_s[tid*4] = ldcv4(&ws[OFF_WW + b*256 + tid*4]); }
        else if (tid >= 384 && tid < 496)  { const int i = tid-384; *(float4*)&pk_s[i*4] = ldcv4(&ws[OFF_PARSE + b*448 + i*4]); }
        __syncthreads();

        // ---- M update + norms + cr logits (uses preloaded m_pre) ----
        {
            const int ric = tid >> 4, c4 = (tid & 15) * 4;
            const int gi  = c * 32 + ric;
            float* mp = ws + OFF_M + b * (TN*TWM) + gi * 64 + c4;
            float4 m = m_pre;
            const float wwi = ww_s[gi];
            float4 er = *(const float4*)&pk_s[256 + c4];
            float4 wv = *(const float4*)&pk_s[320 + c4];
            m.x = m.x * (1.0f - wwi * er.x) + wwi * wv.x;
            m.y = m.y * (1.0f - wwi * er.y) + wwi * wv.y;
            m.z = m.z * (1.0f - wwi * er.z) + wwi * wv.z;
            m.w = m.w * (1.0f - wwi * er.w) + wwi * wv.w;
            stcv4(mp, m);
            float sn = m.x*m.x + m.y*m.y + m.z*m.z + m.w*m.w;
            float d0 = m.x*pk_s[c4]     + m.y*pk_s[c4+1]     + m.z*pk_s[c4+2]     + m.w*pk_s[c4+3];
            float d1 = m.x*pk_s[64+c4]  + m.y*pk_s[64+c4+1]  + m.z*pk_s[64+c4+2]  + m.w*pk_s[64+c4+3];
            float d2 = m.x*pk_s[128+c4] + m.y*pk_s[128+c4+1] + m.z*pk_s[128+c4+2] + m.w*pk_s[128+c4+3];
            float d3 = m.x*pk_s[192+c4] + m.y*pk_s[192+c4+1] + m.z*pk_s[192+c4+2] + m.w*pk_s[192+c4+3];
            #pragma unroll
            for (int mm = 1; mm <= 8; mm <<= 1) {
                sn += __shfl_xor(sn, mm);
                d0 += __shfl_xor(d0, mm); d1 += __shfl_xor(d1, mm);
                d2 += __shfl_xor(d2, mm); d3 += __shfl_xor(d3, mm);
            }
            if ((tid & 15) == 0) {
                const float mn = fmaxf(sqrtf(sn), EPSI);
                ws[OFF_MNORM + b*256 + gi] = mn;   // next dispatch: plain
                const float inv = 1.0f / mn;
                stc(&ws[OFF_CRS + b*1024 + 0*256 + gi], pk_s[384+0] * d0 * inv / pk_s[388+0]);
                stc(&ws[OFF_CRS + b*1024 + 1*256 + gi], pk_s[384+1] * d1 * inv / pk_s[388+1]);
                stc(&ws[OFF_CRS + b*1024 + 2*256 + gi], pk_s[384+2] * d2 * inv / pk_s[388+2]);
                stc(&ws[OFF_CRS + b*1024 + 3*256 + gi], pk_s[384+3] * d3 * inv / pk_s[388+3]);
            }
        }

        // ---- link rows update (uses preloaded lpre; plain write, block-local) ----
        {
            const int j = tid & 255, p = tid >> 8;
            const float wwj = ww_s[j], pj = prec_s[j];
            #pragma unroll 4
            for (int it = 0; it < 16; ++it) {
                const int ric = it * 2 + p;
                const int gi  = c * 32 + ric;
                float* lp = ws + OFF_LINK + (size_t)b * (TN*TN) + (size_t)gi * 256 + j;
                const float wwi = ww_s[gi];
                float v = (1.0f - wwi - wwj) * lpre[it] + wwi * pj;
                if (j == gi) v = 0.0f;
                *lp = v;
                Lt[ric * 257 + j] = v;
            }
        }
        __syncthreads();

        // ---- fw ----
        {
            const int ric = tid >> 4, g = tid & 15;
            const int gi = c * 32 + ric;
            float f0=0, f1=0, f2=0, f3=0;
            #pragma unroll 4
            for (int jj = 0; jj < 16; ++jj) {
                const int j = g * 16 + jj;
                const float v = Lt[ric * 257 + j];
                f0 += v * rw_s[j]; f1 += v * rw_s[256+j];
                f2 += v * rw_s[512+j]; f3 += v * rw_s[768+j];
            }
            #pragma unroll
            for (int mm = 1; mm <= 8; mm <<= 1) {
                f0 += __shfl_xor(f0, mm); f1 += __shfl_xor(f1, mm);
                f2 += __shfl_xor(f2, mm); f3 += __shfl_xor(f3, mm);
            }
            if (g == 0) {
                stc(&ws[OFF_FW + b*1024 + gi],       f0);
                stc(&ws[OFF_FW + b*1024 + 256 + gi], f1);
                stc(&ws[OFF_FW + b*1024 + 512 + gi], f2);
                stc(&ws[OFF_FW + b*1024 + 768 + gi], f3);
            }
        }

        // ---- bw partials ----
        {
            const int j = tid & 255, p = tid >> 8;
            float b0=0, b1=0, b2=0, b3=0;
            #pragma unroll 4
            for (int it = 0; it < 16; ++it) {
                const int ric = p * 16 + it;
                const int gi  = c * 32 + ric;
                const float v = Lt[ric * 257 + j];
                b0 += v * rw_s[gi]; b1 += v * rw_s[256+gi];
                b2 += v * rw_s[512+gi]; b3 += v * rw_s[768+gi];
            }
            __syncthreads();
            if (p == 1) { Lt[j] = b0; Lt[256+j] = b1; Lt[512+j] = b2; Lt[768+j] = b3; }
            __syncthreads();
            if (p == 0) {
                stc(&ws[OFF_BWP + (size_t)blk*1024 + j],       b0 + Lt[j]);
                stc(&ws[OFF_BWP + (size_t)blk*1024 + 256 + j], b1 + Lt[256+j]);
                stc(&ws[OFF_BWP + (size_t)blk*1024 + 512 + j], b2 + Lt[512+j]);
                stc(&ws[OFF_BWP + (size_t)blk*1024 + 768 + j], b3 + Lt[768+j]);
            }
        }
    }

    // ===== stepB tail (last of the 8 chunk blocks per batch) =====
    asm volatile("s_waitcnt vmcnt(0)" ::: "memory");
    __syncthreads();
    if (tid == 0) {
        unsigned* cnt = (unsigned*)(ws + CNT_SB(b));
        const unsigned old = __hip_atomic_fetch_add(cnt, 1u, __ATOMIC_RELAXED, __HIP_MEMORY_SCOPE_AGENT);
        isTail = (old == 8u * (unsigned)t + 7u) ? 1 : 0;
    }
    __syncthreads();
    if (!isTail) return;
    stepB_fn(ws, t, b, tid, sm);
}

extern "C" void kernel_launch(void* const* d_in, const int* in_sizes, int n_in,
                              void* d_out, int out_size, void* d_ws, size_t ws_size,
                              hipStream_t stream) {
    const float* emb    = (const float*)d_in[0];
    const float* Wx     = (const float*)d_in[1];
    const float* Wh     = (const float*)d_in[2];
    const float* b_lstm = (const float*)d_in[3];
    const float* W_pre  = (const float*)d_in[4];
    const float* b_pre  = (const float*)d_in[5];
    const float* W_if   = (const float*)d_in[6];
    const float* b_if   = (const float*)d_in[7];
    const float* W_rout = (const float*)d_in[8];
    float* out = (float*)d_out;
    float* ws  = (float*)d_ws;

    k_init<<<(TOTAL_STATE + 255) / 256, 256, 0, stream>>>(ws);
    for (int t = 0; t < TT; ++t) {
        k_all<<<256, 512, 0, stream>>>(emb, Wx, Wh, b_lstm, W_pre, b_pre, W_rout,
                                       W_if, b_if, ws, out, t);
    }
    // final out(127): blocks 0..127 idle, blocks 128..255 write row 127
    k_all<<<256, 512, 0, stream>>>(emb, Wx, Wh, b_lstm, W_pre, b_pre, W_rout,
                                   W_if, b_if, ws, out, TT);
}